// Round 12
// baseline (64.658 us; speedup 1.0000x reference)
//
#include <hip/hip_runtime.h>
#include <stdint.h>

// DSN few-shot classifier, MI355X.
// out[q][w] = log_softmax_w( s_w ),  s_w = z_w^T Ghat_w z_w,
// z_w = M_w^T q (raw support dots),  Ghat = G^{-1} - vhat vhat^T,
// vhat = v_min / sqrt(v^T G v).   (Equivalent to ||P9 q||^2 up to the
// query-norm constant, which cancels in softmax.)
//
// R11: the 10x10 solve's output is needed ONLY by the tiny epilogue, not by
// the big GEMM. Solve blocks (5) run INSIDE the GEMM kernel concurrently
// with 256 GEMM blocks -> solve latency (the stubborn ~40us DVFS-throttled
// chain of R1-R10) is hidden under parallel work.
//
// ws layout:
//   [0,      4000)   G    : 5*100 double
//   [4096,   6096)   Ghat : 5*100 float
//   [8192,   172032) P    : 80*1024 bf16 (way w rows 16w..16w+9; rest zero)
//   [262144, 5505024) Z   : [80][16384] float  (row s-major for coalesced epilogue)

typedef __attribute__((ext_vector_type(4))) float f32x4;
typedef __attribute__((ext_vector_type(8))) short s16x8;

#define WS_G_OFF    0
#define WS_GH_OFF   4096
#define WS_P_OFF    8192
#define WS_Z_OFF    262144

__device__ __forceinline__ unsigned short f2bf(float f) {
  unsigned int u = __float_as_uint(f);
  u += 0x7FFFu + ((u >> 16) & 1u);   // round-to-nearest-even
  return (unsigned short)(u >> 16);
}

// int64 vs int32 one-hot labels detection (validated R0).
__device__ __forceinline__ bool labels_int64(const int* L) {
  int cnt = 0; bool oddz = true;
  #pragma unroll
  for (int t = 0; t < 20; ++t) {
    int v = L[t];
    if (t & 1) { if (v) oddz = false; }
    else       { if (v) cnt++; }
  }
  return oddz && (cnt == 2);
}

__device__ __forceinline__ int cls_of(const int* L, bool is64, int i) {
  int best = -0x7fffffff, c = 0;
  #pragma unroll
  for (int j = 0; j < 5; ++j) {
    int v = is64 ? L[i * 10 + 2 * j] : L[i * 5 + j];
    if (v > best) { best = v; c = j; }
  }
  return c;
}

// ---- Kernel 1: gram (blocks 0..68) + pack P (blocks 69..148) --------------
__global__ __launch_bounds__(256) void dsn_prep(const float* __restrict__ support,
                                                const int* __restrict__ labels,
                                                double* __restrict__ G,
                                                unsigned short* __restrict__ P) {
  int b = blockIdx.x;
  bool is64 = labels_int64(labels);

  if (b < 69) {                        // ---- gram: one wave per (w,a,b) pair
    int wid  = b * 4 + (threadIdx.x >> 6);
    int lane = threadIdx.x & 63;
    if (wid >= 275) return;
    int w = wid / 55, p = wid % 55;
    int a = 0;
    while (p >= 10 - a) { p -= 10 - a; a++; }
    int bb = a + p;

    int myc = (lane < 50) ? cls_of(labels, is64, lane) : -1;
    unsigned long long mask = __ballot(lane < 50 && myc == w);

    unsigned long long m = mask;
    for (int i = 0; i < a; ++i) m &= m - 1;
    int ia = __ffsll((unsigned long long)m) - 1;
    m = mask;
    for (int i = 0; i < bb; ++i) m &= m - 1;
    int ib = __ffsll((unsigned long long)m) - 1;

    const float* A = support + ia * 1024;
    const float* B = support + ib * 1024;
    double acc = 0.0;
    #pragma unroll
    for (int i = 0; i < 16; ++i) {
      int d = lane + 64 * i;
      acc += (double)A[d] * (double)B[d];
    }
    #pragma unroll
    for (int off = 32; off > 0; off >>= 1) acc += __shfl_xor(acc, off);
    if (lane == 0) {
      G[(w * 10 + a) * 10 + bb] = acc;
      G[(w * 10 + bb) * 10 + a] = acc;
    }
  } else {                             // ---- pack: one block per P row
    int r = b - 69;                    // 0..79
    int w = r >> 4, kk = r & 15;
    int t = threadIdx.x;
    unsigned short* Prow = P + r * 1024;
    if (kk >= 10) {                    // zero-pad rows (block-uniform)
      #pragma unroll
      for (int j = 0; j < 4; ++j) Prow[t + 256 * j] = 0;
      return;
    }
    __shared__ int sid;
    if (t < 64) {
      int myc = (t < 50) ? cls_of(labels, is64, t) : -1;
      unsigned long long mask = __ballot(t < 50 && myc == w);
      if (t == 0) {
        unsigned long long m = mask;
        for (int z = 0; z < kk; ++z) m &= m - 1;
        sid = __ffsll(m) - 1;
      }
    }
    __syncthreads();
    const float* src = support + (size_t)sid * 1024;
    #pragma unroll
    for (int j = 0; j < 4; ++j) Prow[t + 256 * j] = f2bf(src[t + 256 * j]);
  }
}

// ---- solve for one way (device fn; whole 256-thread block participates) ---
// R10-validated numerics: NS G^{-1/2} (6 iters) + 8 power-squarings for v.
// Output: Ghat[w*100+e] = (G^{-1} - vhat vhat^T)[e].
__device__ void solve_way(const double* __restrict__ G, float* __restrict__ Ghat,
                          int w) {
  __shared__ float Gf[100], Ysm[100], Zsm[100], Psm[100];
  __shared__ float red[16];
  __shared__ int   jm[1];

  int t = threadIdx.x;
  bool act = (t < 50);
  int e0 = 2 * t, e1 = 2 * t + 1;
  int i0 = e0 / 10, j0 = e0 % 10;
  int i1 = e1 / 10, j1 = e1 % 10;
  if (!act) { e0 = 0; e1 = 1; i0 = 0; j0 = 0; i1 = 0; j1 = 1; }

  if (act) {
    Gf[e0] = (float)G[w * 100 + e0];
    Gf[e1] = (float)G[w * 100 + e1];
  }
  __syncthreads();

  if (t < 10) {
    float r = 0.f;
    #pragma unroll
    for (int k = 0; k < 10; ++k) r += fabsf(Gf[t * 10 + k]);
    red[t] = r;
  }
  __syncthreads();
  float c = red[0];
  #pragma unroll
  for (int k = 1; k < 10; ++k) c = fmaxf(c, red[k]);
  float cinv = 1.f / c;

  if (act) {
    Ysm[e0] = Gf[e0] * cinv;  Ysm[e1] = Gf[e1] * cinv;
    Zsm[e0] = (i0 == j0) ? 1.f : 0.f;
    Zsm[e1] = (i1 == j1) ? 1.f : 0.f;
  }
  __syncthreads();

  #pragma unroll 1
  for (int it = 0; it < 6; ++it) {
    if (act) {
      float p0 = 0.f, p1 = 0.f;
      #pragma unroll
      for (int k = 0; k < 10; ++k) {
        p0 += Zsm[i0 * 10 + k] * Ysm[k * 10 + j0];
        p1 += Zsm[i1 * 10 + k] * Ysm[k * 10 + j1];
      }
      Psm[e0] = p0; Psm[e1] = p1;
    }
    __syncthreads();
    float y0 = 0.f, y1 = 0.f, z0 = 0.f, z1 = 0.f;
    if (act) {
      float ay0 = 0.f, az0 = 0.f, ay1 = 0.f, az1 = 0.f;
      #pragma unroll
      for (int k = 0; k < 10; ++k) {
        ay0 += Ysm[i0 * 10 + k] * Psm[k * 10 + j0];
        az0 += Psm[i0 * 10 + k] * Zsm[k * 10 + j0];
        ay1 += Ysm[i1 * 10 + k] * Psm[k * 10 + j1];
        az1 += Psm[i1 * 10 + k] * Zsm[k * 10 + j1];
      }
      y0 = 1.5f * Ysm[e0] - 0.5f * ay0;
      z0 = 1.5f * Zsm[e0] - 0.5f * az0;
      y1 = 1.5f * Ysm[e1] - 0.5f * ay1;
      z1 = 1.5f * Zsm[e1] - 0.5f * az1;
    }
    __syncthreads();
    if (act) { Ysm[e0] = y0; Ysm[e1] = y1; Zsm[e0] = z0; Zsm[e1] = z1; }
    __syncthreads();
  }
  // Zsm = S^{-1/2}; G^{-1} = Zsm*Zsm * cinv (computed at the end)

  // v_min via repeated squaring of T = I - S
  if (act) {
    Ysm[e0] = ((i0 == j0) ? 1.f : 0.f) - Gf[e0] * cinv;
    Ysm[e1] = ((i1 == j1) ? 1.f : 0.f) - Gf[e1] * cinv;
  }
  __syncthreads();
  #pragma unroll 1
  for (int sq = 0; sq < 8; ++sq) {
    if (act) {
      float p0 = 0.f, p1 = 0.f;
      #pragma unroll
      for (int k = 0; k < 10; ++k) {
        p0 += Ysm[i0 * 10 + k] * Ysm[k * 10 + j0];
        p1 += Ysm[i1 * 10 + k] * Ysm[k * 10 + j1];
      }
      Psm[e0] = p0; Psm[e1] = p1;
    }
    __syncthreads();
    if (t < 10) {
      float m = 0.f;
      #pragma unroll
      for (int k = 0; k < 10; ++k) m = fmaxf(m, fabsf(Psm[t * 10 + k]));
      red[t] = m;
    }
    __syncthreads();
    float m = red[0];
    #pragma unroll
    for (int k = 1; k < 10; ++k) m = fmaxf(m, red[k]);
    float minv = 1.f / m;
    if (act) { Ysm[e0] = Psm[e0] * minv; Ysm[e1] = Psm[e1] * minv; }
    __syncthreads();
  }

  if (t == 0) {
    int best = 0; float bv = Ysm[0];
    #pragma unroll
    for (int k = 1; k < 10; ++k) {
      float dk = Ysm[k * 10 + k];
      if (dk > bv) { bv = dk; best = k; }
    }
    jm[0] = best;
  }
  __syncthreads();
  if (t < 10) red[t] = Ysm[t * 10 + jm[0]];   // v
  __syncthreads();
  float denom = 0.f;                           // v^T G v (redundant, uniform)
  #pragma unroll
  for (int a2 = 0; a2 < 10; ++a2) {
    float gv = 0.f;
    #pragma unroll
    for (int k = 0; k < 10; ++k) gv += Gf[a2 * 10 + k] * red[k];
    denom += red[a2] * gv;
  }

  // Ginv*c = Zsm*Zsm  (Zsm untouched by the squaring phase)
  if (act) {
    float p0 = 0.f, p1 = 0.f;
    #pragma unroll
    for (int k = 0; k < 10; ++k) {
      p0 += Zsm[i0 * 10 + k] * Zsm[k * 10 + j0];
      p1 += Zsm[i1 * 10 + k] * Zsm[k * 10 + j1];
    }
    Psm[e0] = p0; Psm[e1] = p1;
  }
  __syncthreads();
  float rs = rsqrtf(denom);
  if (act) {
    Ghat[w * 100 + e0] = Psm[e0] * cinv - (red[i0] * rs) * (red[j0] * rs);
    Ghat[w * 100 + e1] = Psm[e1] * cinv - (red[i1] * rs) * (red[j1] * rs);
  }
}

// ---- Kernel 2: Z-GEMM (blocks 0..255) || solve (blocks 256..260) ----------
// Z[s_global][q] = sum_d P[s_global][d] * q[d], s_global = w*16 + s.
__global__ __launch_bounds__(256) void dsn_zgemm(const float* __restrict__ query,
                                                 const unsigned short* __restrict__ P,
                                                 const double* __restrict__ G,
                                                 float* __restrict__ Ghat,
                                                 float* __restrict__ Z) {
  if (blockIdx.x >= 256) {             // solve blocks (latency hidden by GEMM)
    solve_way(G, Ghat, blockIdx.x - 256);
    return;
  }
  int wid  = blockIdx.x * 4 + (threadIdx.x >> 6);
  int lane = threadIdx.x & 63;
  int q0   = wid * 16;
  int qrow = lane & 15;
  int kbase = (lane >> 4) * 8;

  const float* qp = query + (size_t)(q0 + qrow) * 1024 + kbase;
  const unsigned short* up = P + qrow * 1024 + kbase;

  f32x4 acc[5];
  #pragma unroll
  for (int w = 0; w < 5; ++w) acc[w] = (f32x4){0.f, 0.f, 0.f, 0.f};

  #pragma unroll 4
  for (int kt = 0; kt < 32; ++kt) {
    const float* qk = qp + kt * 32;
    f32x4 lo = *(const f32x4*)qk;
    f32x4 hi = *(const f32x4*)(qk + 4);
    s16x8 bf;
    bf[0] = (short)f2bf(lo[0]); bf[1] = (short)f2bf(lo[1]);
    bf[2] = (short)f2bf(lo[2]); bf[3] = (short)f2bf(lo[3]);
    bf[4] = (short)f2bf(hi[0]); bf[5] = (short)f2bf(hi[1]);
    bf[6] = (short)f2bf(hi[2]); bf[7] = (short)f2bf(hi[3]);
    const unsigned short* uk = up + kt * 32;
    #pragma unroll
    for (int w = 0; w < 5; ++w) {
      s16x8 av = *(const s16x8*)(uk + w * 16384);   // row w*16 + qrow
      acc[w] = __builtin_amdgcn_mfma_f32_16x16x32_bf16(av, bf, acc[w], 0, 0, 0);
    }
  }

  // store Z: D[row=s][col=q]; row = (lane>>4)*4 + reg, col = lane&15 (m89)
  int rowbase = (lane >> 4) * 4;
  #pragma unroll
  for (int w = 0; w < 5; ++w) {
    #pragma unroll
    for (int r = 0; r < 4; ++r)
      Z[(size_t)(w * 16 + rowbase + r) * 16384 + q0 + qrow] = acc[w][r];
  }
}

// ---- Kernel 3: epilogue — quadratic forms + log_softmax -------------------
__global__ __launch_bounds__(256) void dsn_post(const float* __restrict__ Ghat,
                                                const float* __restrict__ Z,
                                                float* __restrict__ out) {
  __shared__ float Gh[500];
  int t = threadIdx.x;
  for (int i = t; i < 500; i += 256) Gh[i] = Ghat[i];
  __syncthreads();
  int q = blockIdx.x * 256 + t;

  float zv[50];
  #pragma unroll
  for (int w = 0; w < 5; ++w)
    #pragma unroll
    for (int s = 0; s < 10; ++s)
      zv[w * 10 + s] = Z[(size_t)(w * 16 + s) * 16384 + q];   // coalesced

  float sv[5];
  #pragma unroll
  for (int w = 0; w < 5; ++w) {
    float s = 0.f;
    #pragma unroll
    for (int i = 0; i < 10; ++i) {
      float gz = 0.f;
      #pragma unroll
      for (int j = 0; j < 10; ++j) gz += Gh[w * 100 + i * 10 + j] * zv[w * 10 + j];
      s += zv[w * 10 + i] * gz;
    }
    sv[w] = s;
  }
  float mx = fmaxf(fmaxf(fmaxf(sv[0], sv[1]), fmaxf(sv[2], sv[3])), sv[4]);
  float sum = 0.f;
  #pragma unroll
  for (int w = 0; w < 5; ++w) sum += expf(sv[w] - mx);
  float lse = mx + logf(sum);
  float* o = out + (size_t)q * 5;
  #pragma unroll
  for (int w = 0; w < 5; ++w) o[w] = sv[w] - lse;
}

extern "C" void kernel_launch(void* const* d_in, const int* in_sizes, int n_in,
                              void* d_out, int out_size, void* d_ws, size_t ws_size,
                              hipStream_t stream) {
  const float* support = (const float*)d_in[0];
  const int*   labels  = (const int*)d_in[1];
  const float* query   = (const float*)d_in[2];
  float* out = (float*)d_out;
  char* ws = (char*)d_ws;

  double*         G    = (double*)(ws + WS_G_OFF);
  float*          Ghat = (float*)(ws + WS_GH_OFF);
  unsigned short* P    = (unsigned short*)(ws + WS_P_OFF);
  float*          Z    = (float*)(ws + WS_Z_OFF);

  int nq = in_sizes[2] / 1024;          // 16384
  int gemm_blocks = nq / 64;            // 256
  int post_blocks = nq / 256;           // 64

  hipLaunchKernelGGL(dsn_prep,  dim3(149), dim3(256), 0, stream, support, labels, G, P);
  hipLaunchKernelGGL(dsn_zgemm, dim3(gemm_blocks + 5), dim3(256), 0, stream,
                     query, P, G, Ghat, Z);
  hipLaunchKernelGGL(dsn_post,  dim3(post_blocks), dim3(256), 0, stream, Ghat, Z, out);
}